// Round 4
// baseline (583.600 us; speedup 1.0000x reference)
//
#include <hip/hip_runtime.h>

// Problem constants: B=16, F=4096, S=14, NR=16, NTX=4, data syms = 12 (pairs of 6)
#define BF_TOTAL     65536       // 16*4096
#define PAIRS_TOTAL  393216      // BF_TOTAL*6
#define BITS1_OFF    3145728     // BF*48
#define G0_OFF       6291456     // 2*BF*48
#define G1_OFF       7077888     // + BF*12
#define NVAR_OFF     7864320     // + BF*12

struct Cx { float re, im; };

__device__ __forceinline__ Cx cadd(Cx x, Cx y){ return {x.re+y.re, x.im+y.im}; }
__device__ __forceinline__ Cx csub(Cx x, Cx y){ return {x.re-y.re, x.im-y.im}; }
__device__ __forceinline__ Cx cmul(Cx x, Cx y){ return {x.re*y.re - x.im*y.im, x.re*y.im + x.im*y.re}; }
// conj(x)*y
__device__ __forceinline__ Cx cmulc(Cx x, Cx y){ return {x.re*y.re + x.im*y.im, x.re*y.im - x.im*y.re}; }
// x*conj(y)
__device__ __forceinline__ Cx cmulxc(Cx x, Cx y){ return {x.re*y.re + x.im*y.im, x.im*y.re - x.re*y.im}; }
__device__ __forceinline__ Cx cscale(Cx x, float s){ return {x.re*s, x.im*s}; }

// acc += conj(x)*y
__device__ __forceinline__ void macc_c(Cx& o, Cx x, Cx y){
    o.re += x.re*y.re + x.im*y.im;  o.im += x.re*y.im - x.im*y.re;
}
// acc += x*conj(y)
__device__ __forceinline__ void macc_xc(Cx& o, Cx x, Cx y){
    o.re += x.re*y.re + x.im*y.im;  o.im += x.im*y.re - x.re*y.im;
}
// acc -= x*conj(y)
__device__ __forceinline__ void msub_xc(Cx& o, Cx x, Cx y){
    o.re -= x.re*y.re + x.im*y.im;  o.im -= x.im*y.re - x.re*y.im;
}

// 16-QAM Gray hard decision: bits (b0,b1,b2,b3) MSB-first, symbol value
__device__ __forceinline__ void decide(Cx y, float4* bits, Cx* sym){
    const float TH   = 0.63245553203367587f;  // 2/sqrt(10)
    const float L1   = 0.31622776601683794f;  // 1/sqrt(10)
    const float L3   = 0.94868329805051381f;  // 3/sqrt(10)
    bool b0 = y.re < 0.0f;
    bool b2 = fabsf(y.re) > TH;
    bool b1 = y.im < 0.0f;
    bool b3 = fabsf(y.im) > TH;
    float mr = b2 ? L3 : L1;
    float mi = b3 ? L3 : L1;
    sym->re = b0 ? -mr : mr;
    sym->im = b1 ? -mi : mi;
    *bits = make_float4(b0 ? 1.f : 0.f, b1 ? 1.f : 0.f, b2 ? 1.f : 0.f, b3 ? 1.f : 0.f);
}

__device__ __forceinline__ Cx getc(const float4& re, const float4& im, int k){
    switch (k & 3){
        case 0: return {re.x, im.x};
        case 1: return {re.y, im.y};
        case 2: return {re.z, im.z};
        default: return {re.w, im.w};
    }
}

__global__ __launch_bounds__(256) void ncjt_rxue_kernel(
    const float* __restrict__ ryr, const float* __restrict__ ryi,
    const float* __restrict__ hr,  const float* __restrict__ hi,
    float* __restrict__ out)
{
    int p = blockIdx.x * 256 + threadIdx.x;
    if (p >= PAIRS_TOTAL) return;
    int bf = p / 6;
    int pr = p - bf * 6;
    // data-symbol pairs: (0,1),(3,4),(5,6),(7,8),(9,10),(12,13)
    int sA = (pr == 0) ? 0 : ((pr == 5) ? 12 : (2*pr + 1));

    const float* hrA = hr  + (long)bf * 896 + sA * 64;   // [ant][tx] fp, tx contiguous
    const float* hiA = hi  + (long)bf * 896 + sA * 64;
    const float* rrA = ryr + (long)bf * 224 + sA * 16;
    const float* riA = ryi + (long)bf * 224 + sA * 16;

    // ZF accumulators
    float P = 0.f, Q = 0.f;
    Cx E{0,0}, F{0,0}, u0{0,0}, u1{0,0}, u2{0,0}, u3{0,0};
    // cross-sums for case c0 (stream0 better: cb = tx(0,1) per-symbol, g = avg tx(2,3))
    Cx M00t{0,0}, M01t{0,0}, N00t{0,0}, N01t{0,0}, P00t{0,0}, P01t{0,0}, Q00t{0,0}, Q01t{0,0};
    // cross-sums for case !c0
    Cx M00f{0,0}, M01f{0,0}, N00f{0,0}, N01f{0,0}, P00f{0,0}, P01f{0,0}, Q00f{0,0}, Q01f{0,0};

    for (int j = 0; j < 4; ++j){
        float4 rAre = *(const float4*)(rrA + j*4);
        float4 rAim = *(const float4*)(riA + j*4);
        float4 rBre = *(const float4*)(rrA + 16 + j*4);
        float4 rBim = *(const float4*)(riA + 16 + j*4);
        #pragma unroll
        for (int k = 0; k < 4; ++k){
            int r = j*4 + k;
            float4 hAre = *(const float4*)(hrA + r*4);
            float4 hAim = *(const float4*)(hiA + r*4);
            float4 hBre = *(const float4*)(hrA + 64 + r*4);
            float4 hBim = *(const float4*)(hiA + 64 + r*4);

            Cx hA0{hAre.x, hAim.x}, hA1{hAre.y, hAim.y}, hA2{hAre.z, hAim.z}, hA3{hAre.w, hAim.w};
            Cx hB0{hBre.x, hBim.x}, hB1{hBre.y, hBim.y}, hB2{hBre.z, hBim.z}, hB3{hBre.w, hBim.w};
            Cx rA = getc(rAre, rAim, k);
            Cx rB = getc(rBre, rBim, k);

            // averaged channels a,b,c,d (tx 0..3)
            Cx a{(hA0.re + hB0.re)*0.5f, (hA0.im + hB0.im)*0.5f};
            Cx b{(hA1.re + hB1.re)*0.5f, (hA1.im + hB1.im)*0.5f};
            Cx c{(hA2.re + hB2.re)*0.5f, (hA2.im + hB2.im)*0.5f};
            Cx d{(hA3.re + hB3.re)*0.5f, (hA3.im + hB3.im)*0.5f};

            P += a.re*a.re + a.im*a.im + b.re*b.re + b.im*b.im;
            Q += c.re*c.re + c.im*c.im + d.re*d.re + d.im*d.im;

            macc_c (E, a, c);  macc_xc(E, b, d);     // E += conj(a)c + b conj(d)
            macc_c (F, a, d);  msub_xc(F, b, c);     // F += conj(a)d - b conj(c)

            macc_c (u0, a, rA);  macc_xc(u0, b, rB); // u0 += conj(a)rA + b conj(rB)
            macc_c (u1, b, rA);  msub_xc(u1, a, rB);
            macc_c (u2, c, rA);  macc_xc(u2, d, rB);
            macc_c (u3, d, rA);  msub_xc(u3, c, rB);

            // case true: g0=c, g1=d; better per-symbol channels = (hA0,hA1),(hB0,hB1)
            macc_c (M00t, c, hA0);  macc_c (M01t, c, hA1);
            macc_xc(N00t, d, hB0);  macc_xc(N01t, d, hB1);
            macc_c (P00t, d, hA0);  macc_c (P01t, d, hA1);
            macc_xc(Q00t, c, hB0);  macc_xc(Q01t, c, hB1);
            // case false: g0=a, g1=b; better channels = (hA2,hA3),(hB2,hB3)
            macc_c (M00f, a, hA2);  macc_c (M01f, a, hA3);
            macc_xc(N00f, b, hB2);  macc_xc(N01f, b, hB3);
            macc_c (P00f, b, hA2);  macc_c (P01f, b, hA3);
            macc_xc(Q00f, a, hB2);  macc_xc(Q01f, a, hB3);
        }
    }

    // closed-form solve of [[P I, B],[B^H, Q I]] s = u, with B=[[E,F],[-conj F, conj E]]
    float D    = E.re*E.re + E.im*E.im + F.re*F.re + F.im*F.im;
    float invP = 1.0f / P;
    float q    = Q - D * invP;
    float invq = 1.0f / q;

    Cx bh0 = csub(cmulc(E, u0), cmul(F, u1));            // conj(E)u0 - F u1
    Cx bh1 = cadd(cmulc(F, u0), cmul(E, u1));            // conj(F)u0 + E u1
    Cx s2  = cscale(csub(u2, cscale(bh0, invP)), invq);
    Cx s3  = cscale(csub(u3, cscale(bh1, invP)), invq);
    Cx s0  = cscale(csub(u0, cadd(cmul(E, s2), cmul(F, s3))), invP);
    Cx s1t = cadd(u1, csub(cmulxc(s2, F), cmulxc(s3, E))); // u1 + conj(F)s2 - conj(E)s3
    Cx s1  = cscale(s1t, invP);

    bool c0 = (P >= Q);

    // hard-decide the better stream
    float4 bxA_bits, bxB_bits; Cx bxA, bxB;
    decide(c0 ? s0 : s2, &bxA_bits, &bxA);
    decide(c0 ? s1 : s3, &bxB_bits, &bxB);

    // select accumulators for the IC + MRC of the worse stream
    Cx S0  = c0 ? u2 : u0;
    Cx S1  = c0 ? u3 : u1;
    Cx M00 = c0 ? M00t : M00f;  Cx M01 = c0 ? M01t : M01f;
    Cx N00 = c0 ? N00t : N00f;  Cx N01 = c0 ? N01t : N01f;
    Cx P00 = c0 ? P00t : P00f;  Cx P01 = c0 ? P01t : P01f;
    Cx Q00 = c0 ? Q00t : Q00f;  Cx Q01 = c0 ? Q01t : Q01f;
    float gain = c0 ? Q : P;

    Cx e0 = cadd(M00, N01);      // coeff of x^A in s0'
    Cx e1 = csub(M01, N00);      // coeff of x^B in s0'
    Cx f0 = csub(P00, Q01);      // coeff of x^A in s1'
    Cx f1 = cadd(P01, Q00);      // coeff of x^B in s1'

    Cx s0p = csub(S0, cadd(cmul(bxA, e0), cmul(bxB, e1)));
    Cx s1p = csub(S1, cadd(cmul(bxA, f0), cmul(bxB, f1)));

    float invg = 1.0f / gain;
    float4 nA_bits, nB_bits; Cx nA, nB;
    decide(cscale(s0p, invg), &nA_bits, &nA);
    decide(cscale(s1p, invg), &nB_bits, &nB);

    // stream0 / stream1 final bits
    float4 o0A = c0 ? bxA_bits : nA_bits;
    float4 o0B = c0 ? bxB_bits : nB_bits;
    float4 o1A = c0 ? nA_bits  : bxA_bits;
    float4 o1B = c0 ? nB_bits  : bxB_bits;

    long ob = (long)bf * 48 + pr * 8;
    *(float4*)(out + ob)                 = o0A;
    *(float4*)(out + ob + 4)             = o0B;
    *(float4*)(out + BITS1_OFF + ob)     = o1A;
    *(float4*)(out + BITS1_OFF + ob + 4) = o1B;

    long og = (long)bf * 12 + pr * 2;
    *(float2*)(out + G0_OFF + og) = make_float2(P, P);
    *(float2*)(out + G1_OFF + og) = make_float2(Q, Q);

    if (p == 0) out[NVAR_OFF] = 0.4f;
}

extern "C" void kernel_launch(void* const* d_in, const int* in_sizes, int n_in,
                              void* d_out, int out_size, void* d_ws, size_t ws_size,
                              hipStream_t stream) {
    const float* ryr = (const float*)d_in[0];
    const float* ryi = (const float*)d_in[1];
    const float* hr  = (const float*)d_in[2];
    const float* hi  = (const float*)d_in[3];
    float* out = (float*)d_out;
    dim3 grid(PAIRS_TOTAL / 256), block(256);
    hipLaunchKernelGGL(ncjt_rxue_kernel, grid, block, 0, stream, ryr, ryi, hr, hi, out);
}